// Round 1
// baseline (1033.683 us; speedup 1.0000x reference)
//
#include <hip/hip_runtime.h>

#define N_TOT 4096
#define HIDN  1024
#define EMBD  256
#define VOC   1024
#define NSTEP 12

typedef __bf16 bf16;
typedef __bf16 bf16x8 __attribute__((ext_vector_type(8)));
typedef __bf16 bf16x4 __attribute__((ext_vector_type(4)));
typedef float  f32x4  __attribute__((ext_vector_type(4)));

static __device__ __forceinline__ f32x4 mfma16(bf16x8 a, bf16x8 b, f32x4 c) {
  return __builtin_amdgcn_mfma_f32_16x16x32_bf16(a, b, c, 0, 0, 0);
}

// ---------------- prep kernels ----------------

__global__ void cvt_kernel(const float* __restrict__ s, bf16* __restrict__ d, int n) {
  for (int i = blockIdx.x * blockDim.x + threadIdx.x; i < n; i += blockDim.x * gridDim.x)
    d[i] = (bf16)s[i];
}

__global__ void bias_sum_kernel(const float* __restrict__ a, const float* __restrict__ b,
                                float* __restrict__ c, int n) {
  int i = blockIdx.x * blockDim.x + threadIdx.x;
  if (i < n) c[i] = a[i] + b[i];
}

__global__ void fill_e_kernel(const float* __restrict__ sos, bf16* __restrict__ e) {
  for (int i = blockIdx.x * blockDim.x + threadIdx.x; i < N_TOT * EMBD;
       i += blockDim.x * gridDim.x)
    e[i] = (bf16)sos[i & (EMBD - 1)];
}

// ---------------- k1: RNN cell  h = tanh(e@Wih^T + hprev@Whh^T + bias) ----------------
// 128x128 tile, 4 waves (2x2), 16x16x32 MFMA, LDS pad to 40 elems/row.

__global__ __launch_bounds__(256)
void rnn_cell_kernel(const bf16* __restrict__ e,     // [N][EMBD]
                     const bf16* __restrict__ hprev, // [N][HIDN]
                     const bf16* __restrict__ Wih,   // [HIDN][EMBD]
                     const bf16* __restrict__ Whh,   // [HIDN][HIDN]
                     const float* __restrict__ bias, // [HIDN] (b_ih + b_hh)
                     bf16* __restrict__ hnew)        // [N][HIDN]
{
  __shared__ bf16 As[128 * 40];
  __shared__ bf16 Bs[128 * 40];
  const int tid = threadIdx.x;
  const int lane = tid & 63;
  const int w = tid >> 6;
  const int wr = w >> 1, wc = w & 1;
  const int m0 = blockIdx.x * 128;
  const int n0 = blockIdx.y * 128;
  const int lr = lane & 15, lk = lane >> 4;

  f32x4 acc[4][4] = {};

  for (int phase = 0; phase < 2; ++phase) {
    const bf16* __restrict__ A = phase ? hprev : e;
    const bf16* __restrict__ B = phase ? Whh : Wih;
    const int K = phase ? HIDN : EMBD;
    for (int k0 = 0; k0 < K; k0 += 32) {
#pragma unroll
      for (int i = 0; i < 2; ++i) {
        int lin = tid + i * 256;
        int r = lin >> 2, c = (lin & 3) * 8;
        *(bf16x8*)&As[r * 40 + c] = *(const bf16x8*)&A[(size_t)(m0 + r) * K + k0 + c];
        *(bf16x8*)&Bs[r * 40 + c] = *(const bf16x8*)&B[(size_t)(n0 + r) * K + k0 + c];
      }
      __syncthreads();
      bf16x8 af[4], bf[4];
#pragma unroll
      for (int mi = 0; mi < 4; ++mi)
        af[mi] = *(bf16x8*)&As[(wr * 64 + mi * 16 + lr) * 40 + lk * 8];
#pragma unroll
      for (int ni = 0; ni < 4; ++ni)
        bf[ni] = *(bf16x8*)&Bs[(wc * 64 + ni * 16 + lr) * 40 + lk * 8];
#pragma unroll
      for (int mi = 0; mi < 4; ++mi)
#pragma unroll
        for (int ni = 0; ni < 4; ++ni)
          acc[mi][ni] = mfma16(af[mi], bf[ni], acc[mi][ni]);
      __syncthreads();
    }
  }

#pragma unroll
  for (int mi = 0; mi < 4; ++mi) {
    int rowb = m0 + wr * 64 + mi * 16 + lk * 4;
#pragma unroll
    for (int ni = 0; ni < 4; ++ni) {
      int col = n0 + wc * 64 + ni * 16 + lr;
      float bs = bias[col];
#pragma unroll
      for (int j = 0; j < 4; ++j) {
        float v = tanhf(acc[mi][ni][j] + bs);
        hnew[(size_t)(rowb + j) * HIDN + col] = (bf16)v;
      }
    }
  }
}

// ---------------- k2: logits = h@Wout^T + b_out + gumbel -> d_out[:, t, :] ----------------

__global__ __launch_bounds__(256)
void logits_kernel(const bf16* __restrict__ h,    // [N][HIDN]
                   const bf16* __restrict__ Wout, // [VOC][HIDN]
                   const float* __restrict__ bout,
                   const float* __restrict__ gum, // [N][VOC] (step slice)
                   float* __restrict__ out,       // [N][NSTEP][VOC]
                   int step)
{
  __shared__ bf16 As[128 * 40];
  __shared__ bf16 Bs[128 * 40];
  const int tid = threadIdx.x;
  const int lane = tid & 63;
  const int w = tid >> 6;
  const int wr = w >> 1, wc = w & 1;
  const int m0 = blockIdx.x * 128;
  const int n0 = blockIdx.y * 128;
  const int lr = lane & 15, lk = lane >> 4;

  f32x4 acc[4][4] = {};

  for (int k0 = 0; k0 < HIDN; k0 += 32) {
#pragma unroll
    for (int i = 0; i < 2; ++i) {
      int lin = tid + i * 256;
      int r = lin >> 2, c = (lin & 3) * 8;
      *(bf16x8*)&As[r * 40 + c] = *(const bf16x8*)&h[(size_t)(m0 + r) * HIDN + k0 + c];
      *(bf16x8*)&Bs[r * 40 + c] = *(const bf16x8*)&Wout[(size_t)(n0 + r) * HIDN + k0 + c];
    }
    __syncthreads();
    bf16x8 af[4], bf[4];
#pragma unroll
    for (int mi = 0; mi < 4; ++mi)
      af[mi] = *(bf16x8*)&As[(wr * 64 + mi * 16 + lr) * 40 + lk * 8];
#pragma unroll
    for (int ni = 0; ni < 4; ++ni)
      bf[ni] = *(bf16x8*)&Bs[(wc * 64 + ni * 16 + lr) * 40 + lk * 8];
#pragma unroll
    for (int mi = 0; mi < 4; ++mi)
#pragma unroll
      for (int ni = 0; ni < 4; ++ni)
        acc[mi][ni] = mfma16(af[mi], bf[ni], acc[mi][ni]);
    __syncthreads();
  }

#pragma unroll
  for (int mi = 0; mi < 4; ++mi) {
    int rowb = m0 + wr * 64 + mi * 16 + lk * 4;
#pragma unroll
    for (int ni = 0; ni < 4; ++ni) {
      int col = n0 + wc * 64 + ni * 16 + lr;
      float bs = bout[col];
#pragma unroll
      for (int j = 0; j < 4; ++j) {
        int row = rowb + j;
        float v = acc[mi][ni][j] + bs + gum[(size_t)row * VOC + col];
        out[((size_t)row * NSTEP + step) * VOC + col] = v;
      }
    }
  }
}

// ---------------- k3: softmax (in-place on d_out) + e_next = x@Wemb^T + b_emb ----------------
// 16 rows/block, 256 threads (4 waves). LDS x tile padded to 1032 elems/row.

__global__ __launch_bounds__(256)
void softmax_emb_kernel(float* __restrict__ out,       // [N][NSTEP][VOC]
                        const bf16* __restrict__ Wemb, // [EMBD][VOC]
                        const float* __restrict__ bemb,
                        bf16* __restrict__ enext,      // [N][EMBD]
                        int step)
{
  __shared__ bf16 xs[16 * 1032];
  const int tid = threadIdx.x;
  const int lane = tid & 63;
  const int w = tid >> 6;
  const int n0 = blockIdx.x * 16;

  // --- softmax: wave w handles rows {w, w+4, w+8, w+12} ---
  for (int rr = 0; rr < 4; ++rr) {
    int r = w + rr * 4;
    float* rowp = out + ((size_t)(n0 + r) * NSTEP + step) * VOC;
    float s[16];
    float m = -1e30f;
#pragma unroll
    for (int i = 0; i < 4; ++i) {
      f32x4 v = *(const f32x4*)&rowp[i * 256 + lane * 4];
      s[i * 4 + 0] = v.x; s[i * 4 + 1] = v.y; s[i * 4 + 2] = v.z; s[i * 4 + 3] = v.w;
      m = fmaxf(m, fmaxf(fmaxf(v.x, v.y), fmaxf(v.z, v.w)));
    }
#pragma unroll
    for (int off = 32; off; off >>= 1) m = fmaxf(m, __shfl_xor(m, off));
    float sum = 0.f;
#pragma unroll
    for (int i = 0; i < 16; ++i) { s[i] = __expf(s[i] - m); sum += s[i]; }
#pragma unroll
    for (int off = 32; off; off >>= 1) sum += __shfl_xor(sum, off);
    float inv = 1.0f / sum;
#pragma unroll
    for (int i = 0; i < 4; ++i) {
      f32x4 v;
      v.x = s[i * 4 + 0] * inv; v.y = s[i * 4 + 1] * inv;
      v.z = s[i * 4 + 2] * inv; v.w = s[i * 4 + 3] * inv;
      *(f32x4*)&rowp[i * 256 + lane * 4] = v;
      bf16x4 bv;
      bv[0] = (bf16)v.x; bv[1] = (bf16)v.y; bv[2] = (bf16)v.z; bv[3] = (bf16)v.w;
      *(bf16x4*)&xs[r * 1032 + i * 256 + lane * 4] = bv;
    }
  }
  __syncthreads();

  // --- emb GEMM: wave w computes cols [w*64, w*64+64) over 16 rows ---
  const int lr = lane & 15, lk = lane >> 4;
  f32x4 acc[4] = {};
  for (int k0 = 0; k0 < VOC; k0 += 32) {
    bf16x8 a = *(bf16x8*)&xs[lr * 1032 + k0 + lk * 8];
#pragma unroll
    for (int ni = 0; ni < 4; ++ni) {
      int col = w * 64 + ni * 16 + lr;
      bf16x8 b = *(const bf16x8*)&Wemb[(size_t)col * VOC + k0 + lk * 8];
      acc[ni] = mfma16(a, b, acc[ni]);
    }
  }
#pragma unroll
  for (int ni = 0; ni < 4; ++ni) {
    int col = w * 64 + ni * 16 + lr;
    float bb = bemb[col];
#pragma unroll
    for (int j = 0; j < 4; ++j) {
      int n = n0 + lk * 4 + j;
      enext[(size_t)n * EMBD + col] = (bf16)(acc[ni][j] + bb);
    }
  }
}

// ---------------- launch ----------------

extern "C" void kernel_launch(void* const* d_in, const int* in_sizes, int n_in,
                              void* d_out, int out_size, void* d_ws, size_t ws_size,
                              hipStream_t stream) {
  const float* target  = (const float*)d_in[0];
  const float* gumbels = (const float*)d_in[1];
  const float* sos     = (const float*)d_in[2];
  const float* W_ih    = (const float*)d_in[3];
  const float* b_ih    = (const float*)d_in[4];
  const float* W_hh    = (const float*)d_in[5];
  const float* b_hh    = (const float*)d_in[6];
  const float* W_out   = (const float*)d_in[7];
  const float* b_out   = (const float*)d_in[8];
  const float* W_emb   = (const float*)d_in[9];
  const float* b_emb   = (const float*)d_in[10];
  float* out = (float*)d_out;

  char* ws = (char*)d_ws;
  bf16* wih_b  = (bf16*)(ws);                         // 512 KB
  bf16* whh_b  = (bf16*)(ws + (1u << 20));            // 2 MB
  bf16* wout_b = (bf16*)(ws + (3u << 20));            // 2 MB
  bf16* wemb_b = (bf16*)(ws + (5u << 20));            // 512 KB
  float* bias1 = (float*)(ws + (6u << 20));           // 4 KB
  bf16* hbuf0  = (bf16*)(ws + (7u << 20));            // 8 MB
  bf16* hbuf1  = (bf16*)(ws + (15u << 20));           // 8 MB
  bf16* ebuf   = (bf16*)(ws + (23u << 20));           // 2 MB  (total 25 MB)

  auto cvt = [&](const float* s, bf16* d, int n) {
    int blocks = (n + 255) / 256; if (blocks > 2048) blocks = 2048;
    cvt_kernel<<<blocks, 256, 0, stream>>>(s, d, n);
  };
  cvt(W_ih,  wih_b,  HIDN * EMBD);
  cvt(W_hh,  whh_b,  HIDN * HIDN);
  cvt(W_out, wout_b, VOC * HIDN);
  cvt(W_emb, wemb_b, EMBD * VOC);
  cvt(target, hbuf0, N_TOT * HIDN);
  bias_sum_kernel<<<4, 256, 0, stream>>>(b_ih, b_hh, bias1, HIDN);
  fill_e_kernel<<<2048, 256, 0, stream>>>(sos, ebuf);

  bf16* hb[2] = {hbuf0, hbuf1};
  for (int t = 0; t < NSTEP; ++t) {
    bf16* hp = hb[t & 1];
    bf16* hn = hb[(t + 1) & 1];
    rnn_cell_kernel<<<dim3(N_TOT / 128, HIDN / 128), 256, 0, stream>>>(
        ebuf, hp, wih_b, whh_b, bias1, hn);
    logits_kernel<<<dim3(N_TOT / 128, VOC / 128), 256, 0, stream>>>(
        hn, wout_b, b_out, gumbels + (size_t)t * N_TOT * VOC, out, t);
    softmax_emb_kernel<<<N_TOT / 16, 256, 0, stream>>>(out, wemb_b, b_emb, ebuf, t);
  }
}

// Round 2
// 861.888 us; speedup vs baseline: 1.1993x; 1.1993x over previous
//
#include <hip/hip_runtime.h>

#define N_TOT 4096
#define HIDN  1024
#define EMBD  256
#define VOC   1024
#define NSTEP 12

typedef __bf16 bf16;
typedef _Float16 h16;
typedef __bf16 bf16x8 __attribute__((ext_vector_type(8)));
typedef __bf16 bf16x4 __attribute__((ext_vector_type(4)));
typedef _Float16 h16x8 __attribute__((ext_vector_type(8)));
typedef float  f32x4  __attribute__((ext_vector_type(4)));

static __device__ __forceinline__ f32x4 mfma16(bf16x8 a, bf16x8 b, f32x4 c) {
  return __builtin_amdgcn_mfma_f32_16x16x32_bf16(a, b, c, 0, 0, 0);
}

// async global->LDS, 16B per lane. Dest must be wave-uniform base; HW adds lane*16.
static __device__ __forceinline__ void gload16(const bf16* g, bf16* l) {
  __builtin_amdgcn_global_load_lds(
      (const __attribute__((address_space(1))) void*)g,
      (__attribute__((address_space(3))) void*)l, 16, 0, 0);
}

// ---------------- prep kernels ----------------

__global__ void cvt_kernel(const float* __restrict__ s, bf16* __restrict__ d, int n) {
  for (int i = blockIdx.x * blockDim.x + threadIdx.x; i < n; i += blockDim.x * gridDim.x)
    d[i] = (bf16)s[i];
}

__global__ void bias_sum_kernel(const float* __restrict__ a, const float* __restrict__ b,
                                float* __restrict__ c, int n) {
  int i = blockIdx.x * blockDim.x + threadIdx.x;
  if (i < n) c[i] = a[i] + b[i];
}

__global__ void fill_e_kernel(const float* __restrict__ sos, bf16* __restrict__ e) {
  for (int i = blockIdx.x * blockDim.x + threadIdx.x; i < N_TOT * EMBD;
       i += blockDim.x * gridDim.x)
    e[i] = (bf16)sos[i & (EMBD - 1)];
}

// ---------------- k1: RNN cell  h = tanh(e@Wih^T + hprev@Whh^T + bias) ----------------
// 128x64 tile (512 blocks = 2/CU), BK=32, linear LDS + global_load_lds width-16.

__global__ __launch_bounds__(256)
void rnn_cell_kernel(const bf16* __restrict__ e,     // [N][EMBD]
                     const bf16* __restrict__ hprev, // [N][HIDN]
                     const bf16* __restrict__ Wih,   // [HIDN][EMBD]
                     const bf16* __restrict__ Whh,   // [HIDN][HIDN]
                     const float* __restrict__ bias, // [HIDN]
                     bf16* __restrict__ hnew)        // [N][HIDN]
{
  __shared__ bf16 As[128 * 32];
  __shared__ bf16 Bs[64 * 32];
  const int tid = threadIdx.x;
  const int lane = tid & 63;
  const int w = tid >> 6;
  const int wr = w >> 1, wc = w & 1;
  const int m0 = blockIdx.x * 128;
  const int n0 = blockIdx.y * 64;
  const int lr = lane & 15, lk = lane >> 4;
  const int r_a = tid >> 2, c_a = (tid & 3) * 8;   // staging coords (16B/thread)

  f32x4 acc[4][2] = {};

  for (int phase = 0; phase < 2; ++phase) {
    const bf16* __restrict__ A = phase ? hprev : e;
    const bf16* __restrict__ B = phase ? Whh : Wih;
    const int K = phase ? HIDN : EMBD;
    for (int k0 = 0; k0 < K; k0 += 32) {
      gload16(&A[(size_t)(m0 + r_a) * K + k0 + c_a],      As + w * 512);
      gload16(&A[(size_t)(m0 + 64 + r_a) * K + k0 + c_a], As + 2048 + w * 512);
      gload16(&B[(size_t)(n0 + r_a) * K + k0 + c_a],      Bs + w * 512);
      __syncthreads();
      bf16x8 af[4], bfr[2];
#pragma unroll
      for (int mi = 0; mi < 4; ++mi)
        af[mi] = *(bf16x8*)&As[(wr * 64 + mi * 16 + lr) * 32 + lk * 8];
#pragma unroll
      for (int ni = 0; ni < 2; ++ni)
        bfr[ni] = *(bf16x8*)&Bs[(wc * 32 + ni * 16 + lr) * 32 + lk * 8];
#pragma unroll
      for (int mi = 0; mi < 4; ++mi)
#pragma unroll
        for (int ni = 0; ni < 2; ++ni)
          acc[mi][ni] = mfma16(af[mi], bfr[ni], acc[mi][ni]);
      __syncthreads();
    }
  }

#pragma unroll
  for (int mi = 0; mi < 4; ++mi) {
    int rowb = m0 + wr * 64 + mi * 16 + lk * 4;
#pragma unroll
    for (int ni = 0; ni < 2; ++ni) {
      int col = n0 + wc * 32 + ni * 16 + lr;
      float bs = bias[col];
#pragma unroll
      for (int j = 0; j < 4; ++j) {
        float v = tanhf(acc[mi][ni][j] + bs);
        hnew[(size_t)(rowb + j) * HIDN + col] = (bf16)v;
      }
    }
  }
}

// ---------------- k2: logits+gumbel -> fp16 scratch (no d_out write) ----------------

__global__ __launch_bounds__(256)
void logits_kernel(const bf16* __restrict__ h,    // [N][HIDN]
                   const bf16* __restrict__ Wout, // [VOC][HIDN]
                   const float* __restrict__ bout,
                   const float* __restrict__ gum, // [N][VOC] (step slice)
                   h16* __restrict__ lbuf)        // [N][VOC]
{
  __shared__ bf16 As[128 * 32];
  __shared__ bf16 Bs[64 * 32];
  const int tid = threadIdx.x;
  const int lane = tid & 63;
  const int w = tid >> 6;
  const int wr = w >> 1, wc = w & 1;
  const int m0 = blockIdx.x * 128;
  const int n0 = blockIdx.y * 64;
  const int lr = lane & 15, lk = lane >> 4;
  const int r_a = tid >> 2, c_a = (tid & 3) * 8;

  f32x4 acc[4][2] = {};

  for (int k0 = 0; k0 < HIDN; k0 += 32) {
    gload16(&h[(size_t)(m0 + r_a) * HIDN + k0 + c_a],        As + w * 512);
    gload16(&h[(size_t)(m0 + 64 + r_a) * HIDN + k0 + c_a],   As + 2048 + w * 512);
    gload16(&Wout[(size_t)(n0 + r_a) * HIDN + k0 + c_a],     Bs + w * 512);
    __syncthreads();
    bf16x8 af[4], bfr[2];
#pragma unroll
    for (int mi = 0; mi < 4; ++mi)
      af[mi] = *(bf16x8*)&As[(wr * 64 + mi * 16 + lr) * 32 + lk * 8];
#pragma unroll
    for (int ni = 0; ni < 2; ++ni)
      bfr[ni] = *(bf16x8*)&Bs[(wc * 32 + ni * 16 + lr) * 32 + lk * 8];
#pragma unroll
    for (int mi = 0; mi < 4; ++mi)
#pragma unroll
      for (int ni = 0; ni < 2; ++ni)
        acc[mi][ni] = mfma16(af[mi], bfr[ni], acc[mi][ni]);
    __syncthreads();
  }

#pragma unroll
  for (int mi = 0; mi < 4; ++mi) {
    int rowb = m0 + wr * 64 + mi * 16 + lk * 4;
#pragma unroll
    for (int ni = 0; ni < 2; ++ni) {
      int col = n0 + wc * 32 + ni * 16 + lr;
      float bs = bout[col];
#pragma unroll
      for (int j = 0; j < 4; ++j) {
        int row = rowb + j;
        float v = acc[mi][ni][j] + bs + gum[(size_t)row * VOC + col];
        lbuf[(size_t)row * VOC + col] = (h16)v;
      }
    }
  }
}

// ---------------- k3: softmax (fp16 logits -> fp32 d_out) + e_next = x@Wemb^T + b_emb ----

__global__ __launch_bounds__(256)
void softmax_emb_kernel(const h16* __restrict__ lbuf,  // [N][VOC]
                        const bf16* __restrict__ Wemb, // [EMBD][VOC]
                        const float* __restrict__ bemb,
                        float* __restrict__ out,       // [N][NSTEP][VOC]
                        bf16* __restrict__ enext,      // [N][EMBD]
                        int step)
{
  __shared__ bf16 xs[16 * 1032];
  const int tid = threadIdx.x;
  const int lane = tid & 63;
  const int w = tid >> 6;
  const int n0 = blockIdx.x * 16;

  // --- softmax: wave w handles rows {w, w+4, w+8, w+12} ---
  for (int rr = 0; rr < 4; ++rr) {
    int r = w + rr * 4;
    const h16* rowp = lbuf + (size_t)(n0 + r) * VOC;
    float s[16];
    float m = -1e30f;
#pragma unroll
    for (int i = 0; i < 2; ++i) {
      h16x8 v = *(const h16x8*)&rowp[i * 512 + lane * 8];
#pragma unroll
      for (int j = 0; j < 8; ++j) {
        float f = (float)v[j];
        s[i * 8 + j] = f;
        m = fmaxf(m, f);
      }
    }
#pragma unroll
    for (int off = 32; off; off >>= 1) m = fmaxf(m, __shfl_xor(m, off));
    float sum = 0.f;
#pragma unroll
    for (int i = 0; i < 16; ++i) { s[i] = __expf(s[i] - m); sum += s[i]; }
#pragma unroll
    for (int off = 32; off; off >>= 1) sum += __shfl_xor(sum, off);
    float inv = 1.0f / sum;
    float* orow = out + ((size_t)(n0 + r) * NSTEP + step) * VOC;
#pragma unroll
    for (int i = 0; i < 2; ++i) {
      f32x4 v0, v1;
      bf16x8 bv;
#pragma unroll
      for (int j = 0; j < 4; ++j) {
        float x0 = s[i * 8 + j] * inv;
        float x1 = s[i * 8 + 4 + j] * inv;
        v0[j] = x0; v1[j] = x1;
        bv[j] = (bf16)x0; bv[4 + j] = (bf16)x1;
      }
      *(f32x4*)&orow[i * 512 + lane * 8] = v0;
      *(f32x4*)&orow[i * 512 + lane * 8 + 4] = v1;
      *(bf16x8*)&xs[r * 1032 + i * 512 + lane * 8] = bv;
    }
  }
  __syncthreads();

  // --- emb GEMM: wave w computes cols [w*64, w*64+64) over 16 rows ---
  const int lr = lane & 15, lk = lane >> 4;
  f32x4 acc[4] = {};
  for (int k0 = 0; k0 < VOC; k0 += 32) {
    bf16x8 a = *(bf16x8*)&xs[lr * 1032 + k0 + lk * 8];
#pragma unroll
    for (int ni = 0; ni < 4; ++ni) {
      int col = w * 64 + ni * 16 + lr;
      bf16x8 b = *(const bf16x8*)&Wemb[(size_t)col * VOC + k0 + lk * 8];
      acc[ni] = mfma16(a, b, acc[ni]);
    }
  }
#pragma unroll
  for (int ni = 0; ni < 4; ++ni) {
    int col = w * 64 + ni * 16 + lr;
    float bb = bemb[col];
#pragma unroll
    for (int j = 0; j < 4; ++j) {
      int n = n0 + lk * 4 + j;
      enext[(size_t)n * EMBD + col] = (bf16)(acc[ni][j] + bb);
    }
  }
}

// ---------------- launch ----------------

extern "C" void kernel_launch(void* const* d_in, const int* in_sizes, int n_in,
                              void* d_out, int out_size, void* d_ws, size_t ws_size,
                              hipStream_t stream) {
  const float* target  = (const float*)d_in[0];
  const float* gumbels = (const float*)d_in[1];
  const float* sos     = (const float*)d_in[2];
  const float* W_ih    = (const float*)d_in[3];
  const float* b_ih    = (const float*)d_in[4];
  const float* W_hh    = (const float*)d_in[5];
  const float* b_hh    = (const float*)d_in[6];
  const float* W_out   = (const float*)d_in[7];
  const float* b_out   = (const float*)d_in[8];
  const float* W_emb   = (const float*)d_in[9];
  const float* b_emb   = (const float*)d_in[10];
  float* out = (float*)d_out;

  char* ws = (char*)d_ws;
  bf16* wih_b  = (bf16*)(ws);                // 512 KB
  bf16* whh_b  = (bf16*)(ws + (1u << 20));   // 2 MB
  bf16* wout_b = (bf16*)(ws + (3u << 20));   // 2 MB
  bf16* wemb_b = (bf16*)(ws + (5u << 20));   // 512 KB
  float* bias1 = (float*)(ws + (6u << 20));  // 4 KB
  bf16* hbuf0  = (bf16*)(ws + (7u << 20));   // 8 MB
  bf16* hbuf1  = (bf16*)(ws + (15u << 20));  // 8 MB
  bf16* ebuf   = (bf16*)(ws + (23u << 20));  // 2 MB
  h16*  lbuf   = (h16*) (ws + (25u << 20));  // 8 MB  (total 33 MB)

  auto cvt = [&](const float* s, bf16* d, int n) {
    int blocks = (n + 255) / 256; if (blocks > 2048) blocks = 2048;
    cvt_kernel<<<blocks, 256, 0, stream>>>(s, d, n);
  };
  cvt(W_ih,  wih_b,  HIDN * EMBD);
  cvt(W_hh,  whh_b,  HIDN * HIDN);
  cvt(W_out, wout_b, VOC * HIDN);
  cvt(W_emb, wemb_b, EMBD * VOC);
  cvt(target, hbuf0, N_TOT * HIDN);
  bias_sum_kernel<<<4, 256, 0, stream>>>(b_ih, b_hh, bias1, HIDN);
  fill_e_kernel<<<2048, 256, 0, stream>>>(sos, ebuf);

  bf16* hb[2] = {hbuf0, hbuf1};
  for (int t = 0; t < NSTEP; ++t) {
    bf16* hp = hb[t & 1];
    bf16* hn = hb[(t + 1) & 1];
    rnn_cell_kernel<<<dim3(N_TOT / 128, HIDN / 64), 256, 0, stream>>>(
        ebuf, hp, wih_b, whh_b, bias1, hn);
    logits_kernel<<<dim3(N_TOT / 128, VOC / 64), 256, 0, stream>>>(
        hn, wout_b, b_out, gumbels + (size_t)t * N_TOT * VOC, lbuf);
    softmax_emb_kernel<<<N_TOT / 16, 256, 0, stream>>>(
        lbuf, wemb_b, b_emb, out, ebuf, t);
  }
}

// Round 3
// 786.006 us; speedup vs baseline: 1.3151x; 1.0965x over previous
//
#include <hip/hip_runtime.h>

#define N_TOT 4096
#define HIDN  1024
#define EMBD  256
#define VOC   1024
#define NSTEP 12

typedef __bf16 bf16;
typedef _Float16 h16;
typedef __bf16 bf16x8 __attribute__((ext_vector_type(8)));
typedef __bf16 bf16x4 __attribute__((ext_vector_type(4)));
typedef _Float16 h16x8 __attribute__((ext_vector_type(8)));
typedef float  f32x4  __attribute__((ext_vector_type(4)));

static __device__ __forceinline__ f32x4 mfma16(bf16x8 a, bf16x8 b, f32x4 c) {
  return __builtin_amdgcn_mfma_f32_16x16x32_bf16(a, b, c, 0, 0, 0);
}

// async global->LDS, 16B per lane. LDS dest is wave-uniform base + lane*16;
// global source is per-lane (we pre-swizzle it to realize the XOR-swizzled layout).
static __device__ __forceinline__ void gload16(const bf16* g, bf16* l) {
  __builtin_amdgcn_global_load_lds(
      (const __attribute__((address_space(1))) void*)g,
      (__attribute__((address_space(3))) void*)l, 16, 0, 0);
}

// ---------------- prep kernels ----------------

__global__ void cvt_kernel(const float* __restrict__ s, bf16* __restrict__ d, int n) {
  for (int i = blockIdx.x * blockDim.x + threadIdx.x; i < n; i += blockDim.x * gridDim.x)
    d[i] = (bf16)s[i];
}

__global__ void bias_sum_kernel(const float* __restrict__ a, const float* __restrict__ b,
                                float* __restrict__ c, int n) {
  int i = blockIdx.x * blockDim.x + threadIdx.x;
  if (i < n) c[i] = a[i] + b[i];
}

__global__ void fill_e_kernel(const float* __restrict__ sos, bf16* __restrict__ e) {
  for (int i = blockIdx.x * blockDim.x + threadIdx.x; i < N_TOT * EMBD;
       i += blockDim.x * gridDim.x)
    e[i] = (bf16)sos[i & (EMBD - 1)];
}

// ---------------- k1: RNN cell  h = tanh(e@Wih^T + hprev@Whh^T + bias) ----------------
// 128x64 tile, BK=64, 512 blocks (2/CU). XOR-swizzled LDS (st-16-granule, row&7),
// realized via pre-swizzled global source + swizzled ds_read. XCD-swizzled grid.

__global__ __launch_bounds__(256)
void rnn_cell_kernel(const bf16* __restrict__ e,     // [N][EMBD]
                     const bf16* __restrict__ hprev, // [N][HIDN]
                     const bf16* __restrict__ Wih,   // [HIDN][EMBD]
                     const bf16* __restrict__ Whh,   // [HIDN][HIDN]
                     const float* __restrict__ bias, // [HIDN]
                     bf16* __restrict__ hnew)        // [N][HIDN]
{
  __shared__ bf16 As[128 * 64];
  __shared__ bf16 Bs[64 * 64];
  const int tid = threadIdx.x;
  const int lane = tid & 63;
  const int w = tid >> 6;
  const int wr = w >> 1, wc = w & 1;
  // bijective XCD swizzle (gridDim.x % 8 == 0)
  const int id = (blockIdx.x & 7) * (gridDim.x >> 3) + (blockIdx.x >> 3);
  const int m0 = (id >> 4) * 128;   // 32 m-tiles
  const int n0 = (id & 15) * 64;    // 16 n-tiles
  const int lr = lane & 15, lk = lane >> 4;
  const int srow = lane >> 3;                 // 0..7 row within 8-row chunk
  const int scol = (((lane & 7) ^ srow) << 3); // pre-swizzled source col (elems)

  f32x4 acc[4][2] = {};

  for (int phase = 0; phase < 2; ++phase) {
    const bf16* __restrict__ A = phase ? hprev : e;
    const bf16* __restrict__ B = phase ? Whh : Wih;
    const int K = phase ? HIDN : EMBD;
    for (int k0 = 0; k0 < K; k0 += 64) {
#pragma unroll
      for (int r = 0; r < 4; ++r)
        gload16(&A[(size_t)(m0 + r * 32 + w * 8 + srow) * K + k0 + scol],
                As + r * 2048 + w * 512);
#pragma unroll
      for (int r = 0; r < 2; ++r)
        gload16(&B[(size_t)(n0 + r * 32 + w * 8 + srow) * K + k0 + scol],
                Bs + r * 2048 + w * 512);
      __syncthreads();
#pragma unroll
      for (int kk = 0; kk < 2; ++kk) {
        bf16x8 af[4], bfr[2];
#pragma unroll
        for (int mi = 0; mi < 4; ++mi) {
          int row = wr * 64 + mi * 16 + lr;
          af[mi] = *(bf16x8*)&As[row * 64 + ((((kk << 2) | lk) ^ (row & 7)) << 3)];
        }
#pragma unroll
        for (int ni = 0; ni < 2; ++ni) {
          int row = wc * 32 + ni * 16 + lr;
          bfr[ni] = *(bf16x8*)&Bs[row * 64 + ((((kk << 2) | lk) ^ (row & 7)) << 3)];
        }
#pragma unroll
        for (int mi = 0; mi < 4; ++mi)
#pragma unroll
          for (int ni = 0; ni < 2; ++ni)
            acc[mi][ni] = mfma16(af[mi], bfr[ni], acc[mi][ni]);
      }
      __syncthreads();
    }
  }

#pragma unroll
  for (int mi = 0; mi < 4; ++mi) {
    int rowb = m0 + wr * 64 + mi * 16 + lk * 4;
#pragma unroll
    for (int ni = 0; ni < 2; ++ni) {
      int col = n0 + wc * 32 + ni * 16 + lr;
      float bs = bias[col];
#pragma unroll
      for (int j = 0; j < 4; ++j) {
        float v = tanhf(acc[mi][ni][j] + bs);
        hnew[(size_t)(rowb + j) * HIDN + col] = (bf16)v;
      }
    }
  }
}

// ---------------- k2: logits+gumbel -> fp16 scratch ----------------

__global__ __launch_bounds__(256)
void logits_kernel(const bf16* __restrict__ h,    // [N][HIDN]
                   const bf16* __restrict__ Wout, // [VOC][HIDN]
                   const float* __restrict__ bout,
                   const float* __restrict__ gum, // [N][VOC] (step slice)
                   h16* __restrict__ lbuf)        // [N][VOC]
{
  __shared__ bf16 As[128 * 64];
  __shared__ bf16 Bs[64 * 64];
  const int tid = threadIdx.x;
  const int lane = tid & 63;
  const int w = tid >> 6;
  const int wr = w >> 1, wc = w & 1;
  const int id = (blockIdx.x & 7) * (gridDim.x >> 3) + (blockIdx.x >> 3);
  const int m0 = (id >> 4) * 128;
  const int n0 = (id & 15) * 64;
  const int lr = lane & 15, lk = lane >> 4;
  const int srow = lane >> 3;
  const int scol = (((lane & 7) ^ srow) << 3);

  f32x4 acc[4][2] = {};

  for (int k0 = 0; k0 < HIDN; k0 += 64) {
#pragma unroll
    for (int r = 0; r < 4; ++r)
      gload16(&h[(size_t)(m0 + r * 32 + w * 8 + srow) * HIDN + k0 + scol],
              As + r * 2048 + w * 512);
#pragma unroll
    for (int r = 0; r < 2; ++r)
      gload16(&Wout[(size_t)(n0 + r * 32 + w * 8 + srow) * HIDN + k0 + scol],
              Bs + r * 2048 + w * 512);
    __syncthreads();
#pragma unroll
    for (int kk = 0; kk < 2; ++kk) {
      bf16x8 af[4], bfr[2];
#pragma unroll
      for (int mi = 0; mi < 4; ++mi) {
        int row = wr * 64 + mi * 16 + lr;
        af[mi] = *(bf16x8*)&As[row * 64 + ((((kk << 2) | lk) ^ (row & 7)) << 3)];
      }
#pragma unroll
      for (int ni = 0; ni < 2; ++ni) {
        int row = wc * 32 + ni * 16 + lr;
        bfr[ni] = *(bf16x8*)&Bs[row * 64 + ((((kk << 2) | lk) ^ (row & 7)) << 3)];
      }
#pragma unroll
      for (int mi = 0; mi < 4; ++mi)
#pragma unroll
        for (int ni = 0; ni < 2; ++ni)
          acc[mi][ni] = mfma16(af[mi], bfr[ni], acc[mi][ni]);
    }
    __syncthreads();
  }

#pragma unroll
  for (int mi = 0; mi < 4; ++mi) {
    int rowb = m0 + wr * 64 + mi * 16 + lk * 4;
#pragma unroll
    for (int ni = 0; ni < 2; ++ni) {
      int col = n0 + wc * 32 + ni * 16 + lr;
      float bs = bout[col];
#pragma unroll
      for (int j = 0; j < 4; ++j) {
        int row = rowb + j;
        float v = acc[mi][ni][j] + bs + gum[(size_t)row * VOC + col];
        lbuf[(size_t)row * VOC + col] = (h16)v;
      }
    }
  }
}

// ---------------- k3: softmax (fp16 logits -> fp32 d_out) + e_next = x@Wemb^T + b_emb ----

__global__ __launch_bounds__(256)
void softmax_emb_kernel(const h16* __restrict__ lbuf,  // [N][VOC]
                        const bf16* __restrict__ Wemb, // [EMBD][VOC]
                        const float* __restrict__ bemb,
                        float* __restrict__ out,       // [N][NSTEP][VOC]
                        bf16* __restrict__ enext,      // [N][EMBD]
                        int step)
{
  __shared__ bf16 xs[16 * 1032];
  const int tid = threadIdx.x;
  const int lane = tid & 63;
  const int w = tid >> 6;
  const int n0 = blockIdx.x * 16;

  // --- softmax: wave w handles rows {w, w+4, w+8, w+12} ---
  for (int rr = 0; rr < 4; ++rr) {
    int r = w + rr * 4;
    const h16* rowp = lbuf + (size_t)(n0 + r) * VOC;
    float s[16];
    float m = -1e30f;
#pragma unroll
    for (int i = 0; i < 2; ++i) {
      h16x8 v = *(const h16x8*)&rowp[i * 512 + lane * 8];
#pragma unroll
      for (int j = 0; j < 8; ++j) {
        float f = (float)v[j];
        s[i * 8 + j] = f;
        m = fmaxf(m, f);
      }
    }
#pragma unroll
    for (int off = 32; off; off >>= 1) m = fmaxf(m, __shfl_xor(m, off));
    float sum = 0.f;
#pragma unroll
    for (int i = 0; i < 16; ++i) { s[i] = __expf(s[i] - m); sum += s[i]; }
#pragma unroll
    for (int off = 32; off; off >>= 1) sum += __shfl_xor(sum, off);
    float inv = 1.0f / sum;
    float* orow = out + ((size_t)(n0 + r) * NSTEP + step) * VOC;
#pragma unroll
    for (int i = 0; i < 2; ++i) {
      f32x4 v0, v1;
      bf16x8 bv;
#pragma unroll
      for (int j = 0; j < 4; ++j) {
        float x0 = s[i * 8 + j] * inv;
        float x1 = s[i * 8 + 4 + j] * inv;
        v0[j] = x0; v1[j] = x1;
        bv[j] = (bf16)x0; bv[4 + j] = (bf16)x1;
      }
      *(f32x4*)&orow[i * 512 + lane * 8] = v0;
      *(f32x4*)&orow[i * 512 + lane * 8 + 4] = v1;
      *(bf16x8*)&xs[r * 1032 + i * 512 + lane * 8] = bv;
    }
  }
  __syncthreads();

  // --- emb GEMM: wave w computes cols [w*64, w*64+64) over 16 rows ---
  const int lr = lane & 15, lk = lane >> 4;
  f32x4 acc[4] = {};
  for (int k0 = 0; k0 < VOC; k0 += 32) {
    bf16x8 a = *(bf16x8*)&xs[lr * 1032 + k0 + lk * 8];
#pragma unroll
    for (int ni = 0; ni < 4; ++ni) {
      int col = w * 64 + ni * 16 + lr;
      bf16x8 b = *(const bf16x8*)&Wemb[(size_t)col * VOC + k0 + lk * 8];
      acc[ni] = mfma16(a, b, acc[ni]);
    }
  }
#pragma unroll
  for (int ni = 0; ni < 4; ++ni) {
    int col = w * 64 + ni * 16 + lr;
    float bb = bemb[col];
#pragma unroll
    for (int j = 0; j < 4; ++j) {
      int n = n0 + lk * 4 + j;
      enext[(size_t)n * EMBD + col] = (bf16)(acc[ni][j] + bb);
    }
  }
}

// ---------------- launch ----------------

extern "C" void kernel_launch(void* const* d_in, const int* in_sizes, int n_in,
                              void* d_out, int out_size, void* d_ws, size_t ws_size,
                              hipStream_t stream) {
  const float* target  = (const float*)d_in[0];
  const float* gumbels = (const float*)d_in[1];
  const float* sos     = (const float*)d_in[2];
  const float* W_ih    = (const float*)d_in[3];
  const float* b_ih    = (const float*)d_in[4];
  const float* W_hh    = (const float*)d_in[5];
  const float* b_hh    = (const float*)d_in[6];
  const float* W_out   = (const float*)d_in[7];
  const float* b_out   = (const float*)d_in[8];
  const float* W_emb   = (const float*)d_in[9];
  const float* b_emb   = (const float*)d_in[10];
  float* out = (float*)d_out;

  char* ws = (char*)d_ws;
  bf16* wih_b  = (bf16*)(ws);                // 512 KB
  bf16* whh_b  = (bf16*)(ws + (1u << 20));   // 2 MB
  bf16* wout_b = (bf16*)(ws + (3u << 20));   // 2 MB
  bf16* wemb_b = (bf16*)(ws + (5u << 20));   // 512 KB
  float* bias1 = (float*)(ws + (6u << 20));  // 4 KB
  bf16* hbuf0  = (bf16*)(ws + (7u << 20));   // 8 MB
  bf16* hbuf1  = (bf16*)(ws + (15u << 20));  // 8 MB
  bf16* ebuf   = (bf16*)(ws + (23u << 20));  // 2 MB
  h16*  lbuf   = (h16*) (ws + (25u << 20));  // 8 MB  (total 33 MB)

  auto cvt = [&](const float* s, bf16* d, int n) {
    int blocks = (n + 255) / 256; if (blocks > 2048) blocks = 2048;
    cvt_kernel<<<blocks, 256, 0, stream>>>(s, d, n);
  };
  cvt(W_ih,  wih_b,  HIDN * EMBD);
  cvt(W_hh,  whh_b,  HIDN * HIDN);
  cvt(W_out, wout_b, VOC * HIDN);
  cvt(W_emb, wemb_b, EMBD * VOC);
  cvt(target, hbuf0, N_TOT * HIDN);
  bias_sum_kernel<<<4, 256, 0, stream>>>(b_ih, b_hh, bias1, HIDN);
  fill_e_kernel<<<2048, 256, 0, stream>>>(sos, ebuf);

  bf16* hb[2] = {hbuf0, hbuf1};
  for (int t = 0; t < NSTEP; ++t) {
    bf16* hp = hb[t & 1];
    bf16* hn = hb[(t + 1) & 1];
    rnn_cell_kernel<<<(N_TOT / 128) * (HIDN / 64), 256, 0, stream>>>(
        ebuf, hp, wih_b, whh_b, bias1, hn);
    logits_kernel<<<(N_TOT / 128) * (VOC / 64), 256, 0, stream>>>(
        hn, wout_b, b_out, gumbels + (size_t)t * N_TOT * VOC, lbuf);
    softmax_emb_kernel<<<N_TOT / 16, 256, 0, stream>>>(
        lbuf, wemb_b, b_emb, out, ebuf, t);
  }
}

// Round 4
// 753.098 us; speedup vs baseline: 1.3726x; 1.0437x over previous
//
#include <hip/hip_runtime.h>

#define N_TOT 4096
#define HIDN  1024
#define EMBD  256
#define VOC   1024
#define NSTEP 12

typedef __bf16 bf16;
typedef _Float16 h16;
typedef __bf16 bf16x8 __attribute__((ext_vector_type(8)));
typedef __bf16 bf16x4 __attribute__((ext_vector_type(4)));
typedef _Float16 h16x8 __attribute__((ext_vector_type(8)));
typedef float  f32x4  __attribute__((ext_vector_type(4)));

static __device__ __forceinline__ f32x4 mfma16(bf16x8 a, bf16x8 b, f32x4 c) {
  return __builtin_amdgcn_mfma_f32_16x16x32_bf16(a, b, c, 0, 0, 0);
}

// async global->LDS, 16B per lane. LDS dest is wave-uniform base + lane*16;
// global source is per-lane (pre-swizzled to realize the XOR-swizzled layout).
static __device__ __forceinline__ void gload16(const bf16* g, bf16* l) {
  __builtin_amdgcn_global_load_lds(
      (const __attribute__((address_space(1))) void*)g,
      (__attribute__((address_space(3))) void*)l, 16, 0, 0);
}

// ---------------- fused prep kernel (all cvts + bias sum + e0 fill), quad-vectorized ----

__global__ void prep_kernel(const float* __restrict__ Wih, const float* __restrict__ Whh,
                            const float* __restrict__ Wout, const float* __restrict__ Wemb,
                            const float* __restrict__ target, const float* __restrict__ sos,
                            const float* __restrict__ bih, const float* __restrict__ bhh,
                            bf16* __restrict__ wih_b, bf16* __restrict__ whh_b,
                            bf16* __restrict__ wout_b, bf16* __restrict__ wemb_b,
                            bf16* __restrict__ hbuf, bf16* __restrict__ ebuf,
                            float* __restrict__ bias1) {
  // segment boundaries in float4-quads
  // Wih 65536 | Whh 262144 | Wout 262144 | Wemb 65536 | target 1048576 | ebuf 262144 | bias 256
  for (int q = blockIdx.x * blockDim.x + threadIdx.x; q < 1966336;
       q += blockDim.x * gridDim.x) {
    if (q < 1703936) {
      const float* s; bf16* d; int o;
      if (q < 65536)        { s = Wih;    d = wih_b;  o = q; }
      else if (q < 327680)  { s = Whh;    d = whh_b;  o = q - 65536; }
      else if (q < 589824)  { s = Wout;   d = wout_b; o = q - 327680; }
      else if (q < 655360)  { s = Wemb;   d = wemb_b; o = q - 589824; }
      else                  { s = target; d = hbuf;   o = q - 655360; }
      f32x4 v = *(const f32x4*)&s[(size_t)o * 4];
      bf16x4 b; b[0] = (bf16)v.x; b[1] = (bf16)v.y; b[2] = (bf16)v.z; b[3] = (bf16)v.w;
      *(bf16x4*)&d[(size_t)o * 4] = b;
    } else if (q < 1966080) {
      int o = q - 1703936;
      f32x4 v = *(const f32x4*)&sos[(o & 63) * 4];
      bf16x4 b; b[0] = (bf16)v.x; b[1] = (bf16)v.y; b[2] = (bf16)v.z; b[3] = (bf16)v.w;
      *(bf16x4*)&ebuf[(size_t)o * 4] = b;
    } else {
      int o = q - 1966080;
      f32x4 a = *(const f32x4*)&bih[o * 4];
      f32x4 c = *(const f32x4*)&bhh[o * 4];
      f32x4 r; r.x = a.x + c.x; r.y = a.y + c.y; r.z = a.z + c.z; r.w = a.w + c.w;
      *(f32x4*)&bias1[o * 4] = r;
    }
  }
}

// ---------------- k1: RNN cell  h = tanh(e@Wih^T + hprev@Whh^T + bias) ----------------
// 128x64 tile, BK=64, 512 blocks (2/CU), double-buffered LDS 2-phase pipeline:
// stage(t+1) issued before compute(t); one __syncthreads (vmcnt drain) per tile.

__global__ __launch_bounds__(256)
void rnn_cell_kernel(const bf16* __restrict__ e,     // [N][EMBD]
                     const bf16* __restrict__ hprev, // [N][HIDN]
                     const bf16* __restrict__ Wih,   // [HIDN][EMBD]
                     const bf16* __restrict__ Whh,   // [HIDN][HIDN]
                     const float* __restrict__ bias, // [HIDN]
                     bf16* __restrict__ hnew)        // [N][HIDN]
{
  __shared__ bf16 As[2 * 128 * 64];
  __shared__ bf16 Bs[2 * 64 * 64];
  const int tid = threadIdx.x;
  const int lane = tid & 63;
  const int w = tid >> 6;
  const int wr = w >> 1, wc = w & 1;
  const int id = (blockIdx.x & 7) * (gridDim.x >> 3) + (blockIdx.x >> 3);
  const int m0 = (id >> 4) * 128;
  const int n0 = (id & 15) * 64;
  const int lr = lane & 15, lk = lane >> 4;
  const int srow = lane >> 3;
  const int scol = (((lane & 7) ^ srow) << 3);

  auto stage = [&](int t, int bsel) {
    const bf16 *A, *B; int K, k0;
    if (t < 4) { A = e;     B = Wih; K = EMBD; k0 = t << 6; }
    else       { A = hprev; B = Whh; K = HIDN; k0 = (t - 4) << 6; }
    bf16* Ad = As + bsel * 8192 + w * 512;
    bf16* Bd = Bs + bsel * 4096 + w * 512;
#pragma unroll
    for (int r = 0; r < 4; ++r)
      gload16(&A[(size_t)(m0 + r * 32 + w * 8 + srow) * K + k0 + scol], Ad + r * 2048);
#pragma unroll
    for (int r = 0; r < 2; ++r)
      gload16(&B[(size_t)(n0 + r * 32 + w * 8 + srow) * K + k0 + scol], Bd + r * 2048);
  };

  f32x4 acc[4][2] = {};
  stage(0, 0);
  __syncthreads();
  for (int t = 0; t < 20; ++t) {
    if (t < 19) stage(t + 1, (t + 1) & 1);
    const bf16* Ab = As + (t & 1) * 8192;
    const bf16* Bb = Bs + (t & 1) * 4096;
#pragma unroll
    for (int kk = 0; kk < 2; ++kk) {
      bf16x8 af[4], bfr[2];
#pragma unroll
      for (int mi = 0; mi < 4; ++mi) {
        int row = wr * 64 + mi * 16 + lr;
        af[mi] = *(const bf16x8*)&Ab[row * 64 + ((((kk << 2) | lk) ^ (row & 7)) << 3)];
      }
#pragma unroll
      for (int ni = 0; ni < 2; ++ni) {
        int row = wc * 32 + ni * 16 + lr;
        bfr[ni] = *(const bf16x8*)&Bb[row * 64 + ((((kk << 2) | lk) ^ (row & 7)) << 3)];
      }
#pragma unroll
      for (int mi = 0; mi < 4; ++mi)
#pragma unroll
        for (int ni = 0; ni < 2; ++ni)
          acc[mi][ni] = mfma16(af[mi], bfr[ni], acc[mi][ni]);
    }
    __syncthreads();
  }

#pragma unroll
  for (int mi = 0; mi < 4; ++mi) {
    int rowb = m0 + wr * 64 + mi * 16 + lk * 4;
#pragma unroll
    for (int ni = 0; ni < 2; ++ni) {
      int col = n0 + wc * 32 + ni * 16 + lr;
      float bs = bias[col];
#pragma unroll
      for (int j = 0; j < 4; ++j) {
        float v = tanhf(acc[mi][ni][j] + bs);
        hnew[(size_t)(rowb + j) * HIDN + col] = (bf16)v;
      }
    }
  }
}

// ---------------- k2: pure GEMM logits = h@Wout^T + b_out -> fp16 scratch ----------------

__global__ __launch_bounds__(256)
void logits_kernel(const bf16* __restrict__ h,    // [N][HIDN]
                   const bf16* __restrict__ Wout, // [VOC][HIDN]
                   const float* __restrict__ bout,
                   h16* __restrict__ lbuf)        // [N][VOC]
{
  __shared__ bf16 As[2 * 128 * 64];
  __shared__ bf16 Bs[2 * 64 * 64];
  const int tid = threadIdx.x;
  const int lane = tid & 63;
  const int w = tid >> 6;
  const int wr = w >> 1, wc = w & 1;
  const int id = (blockIdx.x & 7) * (gridDim.x >> 3) + (blockIdx.x >> 3);
  const int m0 = (id >> 4) * 128;
  const int n0 = (id & 15) * 64;
  const int lr = lane & 15, lk = lane >> 4;
  const int srow = lane >> 3;
  const int scol = (((lane & 7) ^ srow) << 3);

  auto stage = [&](int t, int bsel) {
    int k0 = t << 6;
    bf16* Ad = As + bsel * 8192 + w * 512;
    bf16* Bd = Bs + bsel * 4096 + w * 512;
#pragma unroll
    for (int r = 0; r < 4; ++r)
      gload16(&h[(size_t)(m0 + r * 32 + w * 8 + srow) * HIDN + k0 + scol], Ad + r * 2048);
#pragma unroll
    for (int r = 0; r < 2; ++r)
      gload16(&Wout[(size_t)(n0 + r * 32 + w * 8 + srow) * HIDN + k0 + scol], Bd + r * 2048);
  };

  f32x4 acc[4][2] = {};
  stage(0, 0);
  __syncthreads();
  for (int t = 0; t < 16; ++t) {
    if (t < 15) stage(t + 1, (t + 1) & 1);
    const bf16* Ab = As + (t & 1) * 8192;
    const bf16* Bb = Bs + (t & 1) * 4096;
#pragma unroll
    for (int kk = 0; kk < 2; ++kk) {
      bf16x8 af[4], bfr[2];
#pragma unroll
      for (int mi = 0; mi < 4; ++mi) {
        int row = wr * 64 + mi * 16 + lr;
        af[mi] = *(const bf16x8*)&Ab[row * 64 + ((((kk << 2) | lk) ^ (row & 7)) << 3)];
      }
#pragma unroll
      for (int ni = 0; ni < 2; ++ni) {
        int row = wc * 32 + ni * 16 + lr;
        bfr[ni] = *(const bf16x8*)&Bb[row * 64 + ((((kk << 2) | lk) ^ (row & 7)) << 3)];
      }
#pragma unroll
      for (int mi = 0; mi < 4; ++mi)
#pragma unroll
        for (int ni = 0; ni < 2; ++ni)
          acc[mi][ni] = mfma16(af[mi], bfr[ni], acc[mi][ni]);
    }
    __syncthreads();
  }

#pragma unroll
  for (int mi = 0; mi < 4; ++mi) {
    int rowb = m0 + wr * 64 + mi * 16 + lk * 4;
#pragma unroll
    for (int ni = 0; ni < 2; ++ni) {
      int col = n0 + wc * 32 + ni * 16 + lr;
      float bs = bout[col];
#pragma unroll
      for (int j = 0; j < 4; ++j) {
        int row = rowb + j;
        lbuf[(size_t)row * VOC + col] = (h16)(acc[mi][ni][j] + bs);
      }
    }
  }
}

// ---------------- k3: softmax((l+g)) -> fp32 d_out + e_next = x@Wemb^T + b_emb ----------
// 512 threads (8 waves): 2 rows/wave softmax, 32 cols/wave emb GEMM.

__global__ __launch_bounds__(512)
void softmax_emb_kernel(const h16* __restrict__ lbuf,  // [N][VOC]
                        const float* __restrict__ gum, // [N][VOC] (step slice)
                        const bf16* __restrict__ Wemb, // [EMBD][VOC]
                        const float* __restrict__ bemb,
                        float* __restrict__ out,       // [N][NSTEP][VOC]
                        bf16* __restrict__ enext,      // [N][EMBD]
                        int step)
{
  __shared__ bf16 xs[16 * 1032];
  const int tid = threadIdx.x;
  const int lane = tid & 63;
  const int w = tid >> 6;       // 0..7
  const int n0 = blockIdx.x * 16;

  // --- softmax: wave w handles rows {w, w+8} ---
  for (int rr = 0; rr < 2; ++rr) {
    int r = w + rr * 8;
    const h16* lrow = lbuf + (size_t)(n0 + r) * VOC;
    const float* grow = gum + (size_t)(n0 + r) * VOC;
    float s[16];
    float m = -1e30f;
#pragma unroll
    for (int i = 0; i < 2; ++i) {
      h16x8 lv = *(const h16x8*)&lrow[i * 512 + lane * 8];
      f32x4 g0 = *(const f32x4*)&grow[i * 512 + lane * 8];
      f32x4 g1 = *(const f32x4*)&grow[i * 512 + lane * 8 + 4];
#pragma unroll
      for (int j = 0; j < 4; ++j) {
        float f0 = (float)lv[j] + g0[j];
        float f1 = (float)lv[4 + j] + g1[j];
        s[i * 8 + j] = f0; s[i * 8 + 4 + j] = f1;
        m = fmaxf(m, fmaxf(f0, f1));
      }
    }
#pragma unroll
    for (int off = 32; off; off >>= 1) m = fmaxf(m, __shfl_xor(m, off));
    float sum = 0.f;
#pragma unroll
    for (int i = 0; i < 16; ++i) { s[i] = __expf(s[i] - m); sum += s[i]; }
#pragma unroll
    for (int off = 32; off; off >>= 1) sum += __shfl_xor(sum, off);
    float inv = 1.0f / sum;
    float* orow = out + ((size_t)(n0 + r) * NSTEP + step) * VOC;
#pragma unroll
    for (int i = 0; i < 2; ++i) {
      f32x4 v0, v1;
      bf16x8 bv;
#pragma unroll
      for (int j = 0; j < 4; ++j) {
        float x0 = s[i * 8 + j] * inv;
        float x1 = s[i * 8 + 4 + j] * inv;
        v0[j] = x0; v1[j] = x1;
        bv[j] = (bf16)x0; bv[4 + j] = (bf16)x1;
      }
      *(f32x4*)&orow[i * 512 + lane * 8] = v0;
      *(f32x4*)&orow[i * 512 + lane * 8 + 4] = v1;
      *(bf16x8*)&xs[r * 1032 + i * 512 + lane * 8] = bv;
    }
  }
  __syncthreads();

  // --- emb GEMM: wave w computes cols [w*32, w*32+32) over 16 rows ---
  const int lr = lane & 15, lk = lane >> 4;
  f32x4 acc[2] = {};
  for (int k0 = 0; k0 < VOC; k0 += 32) {
    bf16x8 a = *(bf16x8*)&xs[lr * 1032 + k0 + lk * 8];
#pragma unroll
    for (int ni = 0; ni < 2; ++ni) {
      int col = w * 32 + ni * 16 + lr;
      bf16x8 b = *(const bf16x8*)&Wemb[(size_t)col * VOC + k0 + lk * 8];
      acc[ni] = mfma16(a, b, acc[ni]);
    }
  }
#pragma unroll
  for (int ni = 0; ni < 2; ++ni) {
    int col = w * 32 + ni * 16 + lr;
    float bb = bemb[col];
#pragma unroll
    for (int j = 0; j < 4; ++j) {
      int n = n0 + lk * 4 + j;
      enext[(size_t)n * EMBD + col] = (bf16)(acc[ni][j] + bb);
    }
  }
}

// ---------------- launch ----------------

extern "C" void kernel_launch(void* const* d_in, const int* in_sizes, int n_in,
                              void* d_out, int out_size, void* d_ws, size_t ws_size,
                              hipStream_t stream) {
  const float* target  = (const float*)d_in[0];
  const float* gumbels = (const float*)d_in[1];
  const float* sos     = (const float*)d_in[2];
  const float* W_ih    = (const float*)d_in[3];
  const float* b_ih    = (const float*)d_in[4];
  const float* W_hh    = (const float*)d_in[5];
  const float* b_hh    = (const float*)d_in[6];
  const float* W_out   = (const float*)d_in[7];
  const float* b_out   = (const float*)d_in[8];
  const float* W_emb   = (const float*)d_in[9];
  const float* b_emb   = (const float*)d_in[10];
  float* out = (float*)d_out;

  char* ws = (char*)d_ws;
  bf16* wih_b  = (bf16*)(ws);                // 512 KB
  bf16* whh_b  = (bf16*)(ws + (1u << 20));   // 2 MB
  bf16* wout_b = (bf16*)(ws + (3u << 20));   // 2 MB
  bf16* wemb_b = (bf16*)(ws + (5u << 20));   // 512 KB
  float* bias1 = (float*)(ws + (6u << 20));  // 4 KB
  bf16* hbuf0  = (bf16*)(ws + (7u << 20));   // 8 MB
  bf16* hbuf1  = (bf16*)(ws + (15u << 20));  // 8 MB
  bf16* ebuf   = (bf16*)(ws + (23u << 20));  // 2 MB
  h16*  lbuf   = (h16*) (ws + (25u << 20));  // 8 MB  (total 33 MB)

  prep_kernel<<<2048, 256, 0, stream>>>(W_ih, W_hh, W_out, W_emb, target, sos,
                                        b_ih, b_hh, wih_b, whh_b, wout_b, wemb_b,
                                        hbuf0, ebuf, bias1);

  bf16* hb[2] = {hbuf0, hbuf1};
  for (int t = 0; t < NSTEP; ++t) {
    bf16* hp = hb[t & 1];
    bf16* hn = hb[(t + 1) & 1];
    rnn_cell_kernel<<<(N_TOT / 128) * (HIDN / 64), 256, 0, stream>>>(
        ebuf, hp, wih_b, whh_b, bias1, hn);
    logits_kernel<<<(N_TOT / 128) * (VOC / 64), 256, 0, stream>>>(
        hn, wout_b, b_out, lbuf);
    softmax_emb_kernel<<<N_TOT / 16, 512, 0, stream>>>(
        lbuf, gumbels + (size_t)t * N_TOT * VOC, wemb_b, b_emb, out, ebuf, t);
  }
}

// Round 5
// 647.754 us; speedup vs baseline: 1.5958x; 1.1626x over previous
//
#include <hip/hip_runtime.h>

#define N_TOT 4096
#define HIDN  1024
#define EMBD  256
#define VOC   1024
#define NSTEP 12

typedef __bf16 bf16;
typedef _Float16 h16;
typedef __bf16 bf16x8 __attribute__((ext_vector_type(8)));
typedef __bf16 bf16x4 __attribute__((ext_vector_type(4)));
typedef _Float16 h16x8 __attribute__((ext_vector_type(8)));
typedef float  f32x4  __attribute__((ext_vector_type(4)));

#define VMCNT(n) asm volatile("s_waitcnt vmcnt(" #n ")" ::: "memory")
#define MEMFENCE() asm volatile("" ::: "memory")

static __device__ __forceinline__ f32x4 mfma16(bf16x8 a, bf16x8 b, f32x4 c) {
  return __builtin_amdgcn_mfma_f32_16x16x32_bf16(a, b, c, 0, 0, 0);
}

// async global->LDS, 16B per lane. LDS dest is wave-uniform base + lane*16;
// global source is per-lane (pre-swizzled to realize the XOR-swizzled layout).
static __device__ __forceinline__ void gload16(const bf16* g, bf16* l) {
  __builtin_amdgcn_global_load_lds(
      (const __attribute__((address_space(1))) void*)g,
      (__attribute__((address_space(3))) void*)l, 16, 0, 0);
}

// ---------------- fused prep kernel ----------------

__global__ void prep_kernel(const float* __restrict__ Wih, const float* __restrict__ Whh,
                            const float* __restrict__ Wout, const float* __restrict__ Wemb,
                            const float* __restrict__ target, const float* __restrict__ sos,
                            const float* __restrict__ bih, const float* __restrict__ bhh,
                            bf16* __restrict__ wih_b, bf16* __restrict__ whh_b,
                            bf16* __restrict__ wout_b, bf16* __restrict__ wemb_b,
                            bf16* __restrict__ hbuf, bf16* __restrict__ ebuf,
                            float* __restrict__ bias1) {
  for (int q = blockIdx.x * blockDim.x + threadIdx.x; q < 1966336;
       q += blockDim.x * gridDim.x) {
    if (q < 1703936) {
      const float* s; bf16* d; int o;
      if (q < 65536)        { s = Wih;    d = wih_b;  o = q; }
      else if (q < 327680)  { s = Whh;    d = whh_b;  o = q - 65536; }
      else if (q < 589824)  { s = Wout;   d = wout_b; o = q - 327680; }
      else if (q < 655360)  { s = Wemb;   d = wemb_b; o = q - 589824; }
      else                  { s = target; d = hbuf;   o = q - 655360; }
      f32x4 v = *(const f32x4*)&s[(size_t)o * 4];
      bf16x4 b; b[0] = (bf16)v.x; b[1] = (bf16)v.y; b[2] = (bf16)v.z; b[3] = (bf16)v.w;
      *(bf16x4*)&d[(size_t)o * 4] = b;
    } else if (q < 1966080) {
      int o = q - 1703936;
      f32x4 v = *(const f32x4*)&sos[(o & 63) * 4];
      bf16x4 b; b[0] = (bf16)v.x; b[1] = (bf16)v.y; b[2] = (bf16)v.z; b[3] = (bf16)v.w;
      *(bf16x4*)&ebuf[(size_t)o * 4] = b;
    } else {
      int o = q - 1966080;
      f32x4 a = *(const f32x4*)&bih[o * 4];
      f32x4 c = *(const f32x4*)&bhh[o * 4];
      f32x4 r; r.x = a.x + c.x; r.y = a.y + c.y; r.z = a.z + c.z; r.w = a.w + c.w;
      *(f32x4*)&bias1[o * 4] = r;
    }
  }
}

// ---------------- k1: RNN cell, 128x128 tile, 512 thr, 4-deep pipeline ----------------

__global__ __launch_bounds__(512)
void rnn_cell_kernel(const bf16* __restrict__ e,     // [N][EMBD]
                     const bf16* __restrict__ hprev, // [N][HIDN]
                     const bf16* __restrict__ Wih,   // [HIDN][EMBD]
                     const bf16* __restrict__ Whh,   // [HIDN][HIDN]
                     const float* __restrict__ bias, // [HIDN]
                     bf16* __restrict__ hnew)        // [N][HIDN]
{
  __shared__ bf16 lds[4 * 16384];   // 128 KB: buf b = A[8192] | B[8192]
  const int tid = threadIdx.x;
  const int lane = tid & 63;
  const int w = tid >> 6;            // 0..7
  const int wr = w >> 2, wc = w & 3;
  const int id = (blockIdx.x & 7) * (gridDim.x >> 3) + (blockIdx.x >> 3);
  const int m0 = (id >> 3) * 128;    // 32 m-tiles
  const int n0 = (id & 7) * 128;     // 8 n-tiles
  const int lr = lane & 15, lk = lane >> 4;
  const int srow = lane >> 3;
  const int scol = (((lane & 7) ^ srow) << 3);

  auto stage = [&](int t, int bsel) {
    const bf16 *A, *B; int K, k0;
    if (t < 4) { A = e;     B = Wih; K = EMBD; k0 = t << 6; }
    else       { A = hprev; B = Whh; K = HIDN; k0 = (t - 4) << 6; }
    bf16* base = lds + bsel * 16384;
#pragma unroll
    for (int r = 0; r < 2; ++r)
      gload16(&A[(size_t)(m0 + w * 16 + r * 8 + srow) * K + k0 + scol],
              base + (w * 16 + r * 8) * 64);
#pragma unroll
    for (int r = 0; r < 2; ++r)
      gload16(&B[(size_t)(n0 + w * 16 + r * 8 + srow) * K + k0 + scol],
              base + 8192 + (w * 16 + r * 8) * 64);
  };

  const int NT = 20;
  f32x4 acc[4][2] = {};
  stage(0, 0); stage(1, 1); stage(2, 2);
  VMCNT(8);                          // tile 0 landed (per-wave)
  for (int t = 0; t < NT; ++t) {
    MEMFENCE();
    __builtin_amdgcn_s_barrier();    // all waves: tile t landed; buf[(t+3)&3] free
    MEMFENCE();
    if (t + 3 < NT) stage(t + 3, (t + 3) & 3);
    if (t <= NT - 4)      VMCNT(8);  // tile t+1 landed per-wave
    else if (t == NT - 3) VMCNT(4);
    else if (t == NT - 2) VMCNT(0);
    const bf16* Ab = lds + (t & 3) * 16384;
    const bf16* Bb = Ab + 8192;
#pragma unroll
    for (int kk = 0; kk < 2; ++kk) {
      bf16x8 af[4], bfr[2];
#pragma unroll
      for (int mi = 0; mi < 4; ++mi) {
        int row = wr * 64 + mi * 16 + lr;
        af[mi] = *(const bf16x8*)&Ab[row * 64 + ((((kk << 2) | lk) ^ (row & 7)) << 3)];
      }
#pragma unroll
      for (int ni = 0; ni < 2; ++ni) {
        int row = wc * 32 + ni * 16 + lr;
        bfr[ni] = *(const bf16x8*)&Bb[row * 64 + ((((kk << 2) | lk) ^ (row & 7)) << 3)];
      }
#pragma unroll
      for (int mi = 0; mi < 4; ++mi)
#pragma unroll
        for (int ni = 0; ni < 2; ++ni)
          acc[mi][ni] = mfma16(af[mi], bfr[ni], acc[mi][ni]);
    }
  }

#pragma unroll
  for (int mi = 0; mi < 4; ++mi) {
    int rowb = m0 + wr * 64 + mi * 16 + lk * 4;
#pragma unroll
    for (int ni = 0; ni < 2; ++ni) {
      int col = n0 + wc * 32 + ni * 16 + lr;
      float bs = bias[col];
#pragma unroll
      for (int j = 0; j < 4; ++j)
        hnew[(size_t)(rowb + j) * HIDN + col] = (bf16)tanhf(acc[mi][ni][j] + bs);
    }
  }
}

// ---------------- k2: logits = h@Wout^T + b_out -> fp16 scratch ----------------

__global__ __launch_bounds__(512)
void logits_kernel(const bf16* __restrict__ h,    // [N][HIDN]
                   const bf16* __restrict__ Wout, // [VOC][HIDN]
                   const float* __restrict__ bout,
                   h16* __restrict__ lbuf)        // [N][VOC]
{
  __shared__ bf16 lds[4 * 16384];
  const int tid = threadIdx.x;
  const int lane = tid & 63;
  const int w = tid >> 6;
  const int wr = w >> 2, wc = w & 3;
  const int id = (blockIdx.x & 7) * (gridDim.x >> 3) + (blockIdx.x >> 3);
  const int m0 = (id >> 3) * 128;
  const int n0 = (id & 7) * 128;
  const int lr = lane & 15, lk = lane >> 4;
  const int srow = lane >> 3;
  const int scol = (((lane & 7) ^ srow) << 3);

  auto stage = [&](int t, int bsel) {
    int k0 = t << 6;
    bf16* base = lds + bsel * 16384;
#pragma unroll
    for (int r = 0; r < 2; ++r)
      gload16(&h[(size_t)(m0 + w * 16 + r * 8 + srow) * HIDN + k0 + scol],
              base + (w * 16 + r * 8) * 64);
#pragma unroll
    for (int r = 0; r < 2; ++r)
      gload16(&Wout[(size_t)(n0 + w * 16 + r * 8 + srow) * HIDN + k0 + scol],
              base + 8192 + (w * 16 + r * 8) * 64);
  };

  const int NT = 16;
  f32x4 acc[4][2] = {};
  stage(0, 0); stage(1, 1); stage(2, 2);
  VMCNT(8);
  for (int t = 0; t < NT; ++t) {
    MEMFENCE();
    __builtin_amdgcn_s_barrier();
    MEMFENCE();
    if (t + 3 < NT) stage(t + 3, (t + 3) & 3);
    if (t <= NT - 4)      VMCNT(8);
    else if (t == NT - 3) VMCNT(4);
    else if (t == NT - 2) VMCNT(0);
    const bf16* Ab = lds + (t & 3) * 16384;
    const bf16* Bb = Ab + 8192;
#pragma unroll
    for (int kk = 0; kk < 2; ++kk) {
      bf16x8 af[4], bfr[2];
#pragma unroll
      for (int mi = 0; mi < 4; ++mi) {
        int row = wr * 64 + mi * 16 + lr;
        af[mi] = *(const bf16x8*)&Ab[row * 64 + ((((kk << 2) | lk) ^ (row & 7)) << 3)];
      }
#pragma unroll
      for (int ni = 0; ni < 2; ++ni) {
        int row = wc * 32 + ni * 16 + lr;
        bfr[ni] = *(const bf16x8*)&Bb[row * 64 + ((((kk << 2) | lk) ^ (row & 7)) << 3)];
      }
#pragma unroll
      for (int mi = 0; mi < 4; ++mi)
#pragma unroll
        for (int ni = 0; ni < 2; ++ni)
          acc[mi][ni] = mfma16(af[mi], bfr[ni], acc[mi][ni]);
    }
  }

#pragma unroll
  for (int mi = 0; mi < 4; ++mi) {
    int rowb = m0 + wr * 64 + mi * 16 + lk * 4;
#pragma unroll
    for (int ni = 0; ni < 2; ++ni) {
      int col = n0 + wc * 32 + ni * 16 + lr;
      float bs = bout[col];
#pragma unroll
      for (int j = 0; j < 4; ++j) {
        int row = rowb + j;
        lbuf[(size_t)row * VOC + col] = (h16)(acc[mi][ni][j] + bs);
      }
    }
  }
}

// ---------------- k3: softmax((l+g)) -> fp32 d_out + e_next = x@Wemb^T + b_emb ----------

__global__ __launch_bounds__(512)
void softmax_emb_kernel(const h16* __restrict__ lbuf,  // [N][VOC]
                        const float* __restrict__ gum, // [N][VOC] (step slice)
                        const bf16* __restrict__ Wemb, // [EMBD][VOC]
                        const float* __restrict__ bemb,
                        float* __restrict__ out,       // [N][NSTEP][VOC]
                        bf16* __restrict__ enext,      // [N][EMBD]
                        int step)
{
  __shared__ bf16 xs[16 * 1032];
  const int tid = threadIdx.x;
  const int lane = tid & 63;
  const int w = tid >> 6;       // 0..7
  const int n0 = blockIdx.x * 16;

  for (int rr = 0; rr < 2; ++rr) {
    int r = w + rr * 8;
    const h16* lrow = lbuf + (size_t)(n0 + r) * VOC;
    const float* grow = gum + (size_t)(n0 + r) * VOC;
    float s[16];
    float m = -1e30f;
#pragma unroll
    for (int i = 0; i < 2; ++i) {
      h16x8 lv = *(const h16x8*)&lrow[i * 512 + lane * 8];
      f32x4 g0 = *(const f32x4*)&grow[i * 512 + lane * 8];
      f32x4 g1 = *(const f32x4*)&grow[i * 512 + lane * 8 + 4];
#pragma unroll
      for (int j = 0; j < 4; ++j) {
        float f0 = (float)lv[j] + g0[j];
        float f1 = (float)lv[4 + j] + g1[j];
        s[i * 8 + j] = f0; s[i * 8 + 4 + j] = f1;
        m = fmaxf(m, fmaxf(f0, f1));
      }
    }
#pragma unroll
    for (int off = 32; off; off >>= 1) m = fmaxf(m, __shfl_xor(m, off));
    float sum = 0.f;
#pragma unroll
    for (int i = 0; i < 16; ++i) { s[i] = __expf(s[i] - m); sum += s[i]; }
#pragma unroll
    for (int off = 32; off; off >>= 1) sum += __shfl_xor(sum, off);
    float inv = 1.0f / sum;
    float* orow = out + ((size_t)(n0 + r) * NSTEP + step) * VOC;
#pragma unroll
    for (int i = 0; i < 2; ++i) {
      f32x4 v0, v1;
      bf16x8 bv;
#pragma unroll
      for (int j = 0; j < 4; ++j) {
        float x0 = s[i * 8 + j] * inv;
        float x1 = s[i * 8 + 4 + j] * inv;
        v0[j] = x0; v1[j] = x1;
        bv[j] = (bf16)x0; bv[4 + j] = (bf16)x1;
      }
      *(f32x4*)&orow[i * 512 + lane * 8] = v0;
      *(f32x4*)&orow[i * 512 + lane * 8 + 4] = v1;
      *(bf16x8*)&xs[r * 1032 + i * 512 + lane * 8] = bv;
    }
  }
  __syncthreads();

  const int lr = lane & 15, lk = lane >> 4;
  f32x4 acc[2] = {};
  for (int k0 = 0; k0 < VOC; k0 += 32) {
    bf16x8 a = *(bf16x8*)&xs[lr * 1032 + k0 + lk * 8];
#pragma unroll
    for (int ni = 0; ni < 2; ++ni) {
      int col = w * 32 + ni * 16 + lr;
      bf16x8 b = *(const bf16x8*)&Wemb[(size_t)col * VOC + k0 + lk * 8];
      acc[ni] = mfma16(a, b, acc[ni]);
    }
  }
#pragma unroll
  for (int ni = 0; ni < 2; ++ni) {
    int col = w * 32 + ni * 16 + lr;
    float bb = bemb[col];
#pragma unroll
    for (int j = 0; j < 4; ++j) {
      int n = n0 + lk * 4 + j;
      enext[(size_t)n * EMBD + col] = (bf16)(acc[ni][j] + bb);
    }
  }
}

// ---------------- launch ----------------

extern "C" void kernel_launch(void* const* d_in, const int* in_sizes, int n_in,
                              void* d_out, int out_size, void* d_ws, size_t ws_size,
                              hipStream_t stream) {
  const float* target  = (const float*)d_in[0];
  const float* gumbels = (const float*)d_in[1];
  const float* sos     = (const float*)d_in[2];
  const float* W_ih    = (const float*)d_in[3];
  const float* b_ih    = (const float*)d_in[4];
  const float* W_hh    = (const float*)d_in[5];
  const float* b_hh    = (const float*)d_in[6];
  const float* W_out   = (const float*)d_in[7];
  const float* b_out   = (const float*)d_in[8];
  const float* W_emb   = (const float*)d_in[9];
  const float* b_emb   = (const float*)d_in[10];
  float* out = (float*)d_out;

  char* ws = (char*)d_ws;
  bf16* wih_b  = (bf16*)(ws);                // 512 KB
  bf16* whh_b  = (bf16*)(ws + (1u << 20));   // 2 MB
  bf16* wout_b = (bf16*)(ws + (3u << 20));   // 2 MB
  bf16* wemb_b = (bf16*)(ws + (5u << 20));   // 512 KB
  float* bias1 = (float*)(ws + (6u << 20));  // 4 KB
  bf16* hbuf0  = (bf16*)(ws + (7u << 20));   // 8 MB
  bf16* hbuf1  = (bf16*)(ws + (15u << 20));  // 8 MB
  bf16* ebuf   = (bf16*)(ws + (23u << 20));  // 2 MB
  h16*  lbuf   = (h16*) (ws + (25u << 20));  // 8 MB

  prep_kernel<<<2048, 256, 0, stream>>>(W_ih, W_hh, W_out, W_emb, target, sos,
                                        b_ih, b_hh, wih_b, whh_b, wout_b, wemb_b,
                                        hbuf0, ebuf, bias1);

  bf16* hb[2] = {hbuf0, hbuf1};
  for (int t = 0; t < NSTEP; ++t) {
    bf16* hp = hb[t & 1];
    bf16* hn = hb[(t + 1) & 1];
    rnn_cell_kernel<<<(N_TOT / 128) * (HIDN / 128), 512, 0, stream>>>(
        ebuf, hp, wih_b, whh_b, bias1, hn);
    logits_kernel<<<(N_TOT / 128) * (VOC / 128), 512, 0, stream>>>(
        hn, wout_b, b_out, lbuf);
    softmax_emb_kernel<<<N_TOT / 16, 512, 0, stream>>>(
        lbuf, gumbels + (size_t)t * N_TOT * VOC, wemb_b, b_emb, out, ebuf, t);
  }
}